// Round 1
// baseline (66.142 us; speedup 1.0000x reference)
//
#include <hip/hip_runtime.h>
#include <hip/hip_fp16.h>

typedef _Float16 half8 __attribute__((ext_vector_type(8)));
typedef float float4v __attribute__((ext_vector_type(4)));

#define E_DIM 300
#define KP 320              // padded K (10 MFMA k-steps of 32)
#define B_ 32
#define C_ 5
#define H_ 50
#define S_ 20
#define KNUM 20
#define NROW_CDD (B_*C_*S_)   // 3200
#define NROW_HIS (B_*H_*S_)   // 32000
#define NH 10                 // h-chunks of 5 h each
#define LDST 656              // LDS row stride bytes (328 fp16; 656/4=164, 164%32=4 -> 2-way max)

// ---------------- Kernel 1: gather + l2-normalize -> fp16 rows (K padded to 320) --------
__global__ __launch_bounds__(64) void gather_norm(const int* __restrict__ cand,
                                                  const int* __restrict__ clk,
                                                  const float* __restrict__ emb,
                                                  _Float16* __restrict__ outH)
{
    int row = blockIdx.x;
    int lane = threadIdx.x;
    int tok = (row < NROW_CDD) ? cand[row] : clk[row - NROW_CDD];
    const float* e = emb + (long)tok * E_DIM;
    float v[5];
    float ss = 0.f;
#pragma unroll
    for (int j = 0; j < 5; ++j) {
        int idx = lane + j * 64;
        float x = (idx < E_DIM) ? e[idx] : 0.f;
        v[j] = x;
        ss += x * x;
    }
#pragma unroll
    for (int off = 32; off; off >>= 1) ss += __shfl_xor(ss, off);
    float scale = 1.0f / fmaxf(sqrtf(ss), 1e-12f);
    _Float16* o = outH + (long)row * KP;
#pragma unroll
    for (int j = 0; j < 5; ++j) {
        int idx = lane + j * 64;
        o[idx] = (_Float16)((idx < E_DIM) ? v[j] * scale : 0.f);
    }
}

// ---------------- Kernel 2: sim GEMM (MFMA fp16) + gaussian kernels + pooling ------------
// grid = (NH, B_), block = 512 (8 waves). LDS ~132.4 KB -> 1 block/CU.
__global__ __launch_bounds__(512, 1) void knrm_main(const _Float16* __restrict__ wsH,
                                                    const float* __restrict__ cpad,
                                                    const float* __restrict__ hpad,
                                                    const float* __restrict__ ltr_w,
                                                    float* __restrict__ partial)
{
    __shared__ __align__(16) char smem[132448];
    char* Abuf = smem;                       // 100 rows * 656 B = 65600
    char* Bbuf = smem + 65600;               // 65600
    float* simS = (float*)smem;              // overlay A after GEMM: 100*101 f32 = 40400 B
    float* lpw  = (float*)(smem + 65600);    // overlay B after GEMM: 10000 f32 = 40000 B
    float* mhis = (float*)(smem + 131200);   // 100 f32
    float* mcdd = (float*)(smem + 131600);   // 100 f32
    float* wl   = (float*)(smem + 132000);   // 100 f32
    float* wred = (float*)(smem + 132400);   // 8 f32

    int b = blockIdx.y, chunk = blockIdx.x;
    int tid = threadIdx.x;

    // Stage A = cdd rows of this b, B = 100 his rows of this (b, chunk)
    const char* gA = (const char*)(wsH + (long)b * 100 * KP);
    const char* gB = (const char*)(wsH + (long)NROW_CDD * KP + ((long)b * 1000 + chunk * 100) * (long)KP);
    for (int i = tid; i < 100 * 40; i += 512) {
        int r = i / 40, c = i - r * 40;
        *(uint4*)(Abuf + r * LDST + c * 16) = *(const uint4*)(gA + r * 640 + c * 16);
        *(uint4*)(Bbuf + r * LDST + c * 16) = *(const uint4*)(gB + r * 640 + c * 16);
    }
    if (tid < 100) {
        mhis[tid] = hpad[b * 1000 + chunk * 100 + tid];
        mcdd[tid] = cpad[b * 100 + tid];
        wl[tid]   = ltr_w[chunk * 100 + tid];
    }
    __syncthreads();

    int wave = tid >> 6, lane = tid & 63;
    int g = lane >> 4, r16 = lane & 15;
    float4v acc[7];

    if (wave < 7) {
#pragma unroll
        for (int m = 0; m < 7; ++m) acc[m] = (float4v){0.f, 0.f, 0.f, 0.f};
        int rB = wave * 16 + r16; if (rB > 99) rB = 99;   // clamp pad rows
#pragma unroll
        for (int k = 0; k < 10; ++k) {
            half8 bf = *(const half8*)(Bbuf + rB * LDST + k * 64 + g * 16);
#pragma unroll
            for (int m = 0; m < 7; ++m) {
                int rA = m * 16 + r16; if (rA > 99) rA = 99;
                half8 af = *(const half8*)(Abuf + rA * LDST + k * 64 + g * 16);
                acc[m] = __builtin_amdgcn_mfma_f32_16x16x32_f16(af, bf, acc[m], 0, 0, 0);
            }
        }
    }
    __syncthreads();

    // write sims (C/D layout: col = lane&15, row = (lane>>4)*4 + j)  [m89-verified]
    if (wave < 7) {
        int col = wave * 16 + r16;
        if (col < 100) {
#pragma unroll
            for (int m = 0; m < 7; ++m) {
#pragma unroll
                for (int j = 0; j < 4; ++j) {
                    int row = m * 16 + g * 4 + j;
                    if (row < 100) simS[row * 101 + col] = acc[m][j];
                }
            }
        }
    }
    __syncthreads();

    // Phase 2: gaussian kernels + pooling. idx = (c*20+s)*100 + hh*20 + kk
    for (int idx = tid; idx < 10000; idx += 512) {
        int row = idx / 100;
        int rem = idx - row * 100;
        int hh = rem / 20;
        int kk = rem - hh * 20;
        float mu = -0.9f + 0.1f * (float)kk;
        float c2 = (kk == 19) ? 500000.0f : 50.0f;
        const float* sp = simS + row * 101 + hh * 20;
        const float* mp = mhis + hh * 20;
        float psum = 0.f;
#pragma unroll 4
        for (int t = 0; t < 20; ++t) {
            float d = sp[t] - mu;
            psum += __expf(-(d * d) * c2) * mp[t];
        }
        float lp = __logf(fmaxf(psum, 1e-10f)) * 0.01f * mcdd[row];
        lpw[idx] = lp * wl[rem];
    }
    __syncthreads();

    // Reduce per candidate c: sum lpw[c*2000 .. c*2000+1999]
    for (int c = 0; c < 5; ++c) {
        float v = 0.f;
        for (int i = tid; i < 2000; i += 512) v += lpw[c * 2000 + i];
#pragma unroll
        for (int off = 32; off; off >>= 1) v += __shfl_down(v, off);
        if (lane == 0) wred[wave] = v;
        __syncthreads();
        if (tid == 0) {
            float s = 0.f;
#pragma unroll
            for (int w = 0; w < 8; ++w) s += wred[w];
            partial[(b * 5 + c) * NH + chunk] = s;
        }
        __syncthreads();
    }
}

// ---------------- Kernel 3: sum chunks + bias + log_softmax over C=5 --------------------
__global__ __launch_bounds__(64) void finalize(const float* __restrict__ partial,
                                               const float* __restrict__ ltr_b,
                                               float* __restrict__ out)
{
    int b = blockIdx.x;
    int tid = threadIdx.x;
    __shared__ float sc[5];
    if (tid < 5) {
        float v = ltr_b[0];
        for (int ch = 0; ch < NH; ++ch) v += partial[(b * 5 + tid) * NH + ch];
        sc[tid] = v;
    }
    __syncthreads();
    if (tid < 5) {
        float m = sc[0];
        for (int i = 1; i < 5; ++i) m = fmaxf(m, sc[i]);
        float s = 0.f;
        for (int i = 0; i < 5; ++i) s += expf(sc[i] - m);
        out[b * 5 + tid] = sc[tid] - m - logf(s);
    }
}

extern "C" void kernel_launch(void* const* d_in, const int* in_sizes, int n_in,
                              void* d_out, int out_size, void* d_ws, size_t ws_size,
                              hipStream_t stream)
{
    const int*   cand = (const int*)d_in[0];
    const int*   clk  = (const int*)d_in[1];
    const float* cpad = (const float*)d_in[2];
    const float* hpad = (const float*)d_in[3];
    const float* emb  = (const float*)d_in[4];
    const float* lw   = (const float*)d_in[5];
    const float* lb   = (const float*)d_in[6];
    float* out = (float*)d_out;

    _Float16* wsH = (_Float16*)d_ws;
    float* partial = (float*)((char*)d_ws + (size_t)(NROW_CDD + NROW_HIS) * KP * 2);

    hipLaunchKernelGGL(gather_norm, dim3(NROW_CDD + NROW_HIS), dim3(64), 0, stream,
                       cand, clk, emb, wsH);
    hipLaunchKernelGGL(knrm_main, dim3(NH, B_), dim3(512), 0, stream,
                       wsH, cpad, hpad, lw, partial);
    hipLaunchKernelGGL(finalize, dim3(B_), dim3(64), 0, stream, partial, lb, out);
}

// Round 2
// 60.108 us; speedup vs baseline: 1.1004x; 1.1004x over previous
//
#include <hip/hip_runtime.h>
#include <hip/hip_fp16.h>

typedef _Float16 half8 __attribute__((ext_vector_type(8)));
typedef _Float16 half4 __attribute__((ext_vector_type(4)));
typedef float float4v __attribute__((ext_vector_type(4)));

#define E_DIM 300
#define KP 320               // padded K (10 MFMA k-steps of 32)
#define B_ 32
#define NROW_CDD 3200        // 32*5*20
#define NROW_HIS 32000       // 32*50*20

// ---------------- Kernel 1: gather + l2-normalize -> fp16 rows (K padded to 320) --------
// 4 rows per block (1 wave per row), grid 8800.
__global__ __launch_bounds__(256) void gather_norm(const int* __restrict__ cand,
                                                   const int* __restrict__ clk,
                                                   const float* __restrict__ emb,
                                                   _Float16* __restrict__ outH)
{
    int row  = blockIdx.x * 4 + (threadIdx.x >> 6);
    int lane = threadIdx.x & 63;
    int tok = (row < NROW_CDD) ? cand[row] : clk[row - NROW_CDD];
    const float* e = emb + (long)tok * E_DIM;
    float v[5];
    float ss = 0.f;
#pragma unroll
    for (int j = 0; j < 5; ++j) {
        int idx = lane + j * 64;
        float x = (idx < E_DIM) ? e[idx] : 0.f;
        v[j] = x;
        ss += x * x;
    }
#pragma unroll
    for (int off = 32; off; off >>= 1) ss += __shfl_xor(ss, off);
    float scale = 1.0f / fmaxf(sqrtf(ss), 1e-12f);
    _Float16* o = outH + (long)row * KP;
#pragma unroll
    for (int j = 0; j < 5; ++j) {
        int idx = lane + j * 64;
        o[idx] = (_Float16)((idx < E_DIM) ? v[j] * scale : 0.f);
    }
}

// ---------------- Kernel 2: sim GEMM, LDS-free, fragments direct from global ------------
// grid (8 ntiles, 32 b), block 256 (4 waves). Wave computes M=112(clamped 100) x N=32.
__global__ __launch_bounds__(256) void sim_gemm(const _Float16* __restrict__ wsH,
                                                _Float16* __restrict__ simW)
{
    int b = blockIdx.y, ntile = blockIdx.x;
    int wave = threadIdx.x >> 6, lane = threadIdx.x & 63;
    int g = lane >> 4, r16 = lane & 15;
    const char* gA = (const char*)(wsH + (size_t)b * 100 * KP);
    const char* gB = (const char*)(wsH + (size_t)NROW_CDD * KP + (size_t)b * 1000 * KP);
    int nbase = ntile * 128 + wave * 32;

    float4v acc[7][2];
#pragma unroll
    for (int m = 0; m < 7; ++m)
#pragma unroll
        for (int n = 0; n < 2; ++n) acc[m][n] = (float4v){0.f, 0.f, 0.f, 0.f};

#pragma unroll
    for (int k = 0; k < 10; ++k) {
        half8 bf[2];
#pragma unroll
        for (int n = 0; n < 2; ++n) {
            int rB = nbase + n * 16 + r16; if (rB > 999) rB = 999;
            bf[n] = *(const half8*)(gB + (size_t)rB * 640 + k * 64 + g * 16);
        }
#pragma unroll
        for (int m = 0; m < 7; ++m) {
            int rA = m * 16 + r16; if (rA > 99) rA = 99;
            half8 af = *(const half8*)(gA + (size_t)rA * 640 + k * 64 + g * 16);
#pragma unroll
            for (int n = 0; n < 2; ++n)
                acc[m][n] = __builtin_amdgcn_mfma_f32_16x16x32_f16(af, bf[n], acc[m][n], 0, 0, 0);
        }
    }
    // C/D layout (m89-verified): col = lane&15 (B-row), row = (lane>>4)*4 + j (A-row)
#pragma unroll
    for (int m = 0; m < 7; ++m) {
        int rowb = m * 16 + g * 4;
#pragma unroll
        for (int n = 0; n < 2; ++n) {
            int col = nbase + n * 16 + r16;
            if (col > 999) continue;
#pragma unroll
            for (int j = 0; j < 4; ++j) {
                int r = rowb + j;
                if (r < 100) simW[((size_t)b * 100 + r) * 1000 + col] = (_Float16)acc[m][n][j];
            }
        }
    }
}

// ---------------- Kernel 3: gaussian kernels + log pooling, one block per cdd row -------
// grid 3200, block 256 (250 active). Thread: one h (20 t in regs), 4 k's.
__global__ __launch_bounds__(256) void knrm_pool(const _Float16* __restrict__ simW,
                                                 const float* __restrict__ cpad,
                                                 const float* __restrict__ hpad,
                                                 const float* __restrict__ ltr_w,
                                                 float* __restrict__ rowsum)
{
    __shared__ float sS[50 * 21];
    __shared__ float mS[50 * 21];
    __shared__ float wS[1000];
    __shared__ float part[4];

    int row = blockIdx.x;          // (b*5+c)*20 + s
    int b = row / 100;
    int tid = threadIdx.x;

    if (tid < 250) {
        int p = tid * 4;
        half4 hv = *(const half4*)(simW + (size_t)row * 1000 + p);
        float4v mv = *(const float4v*)(hpad + (size_t)b * 1000 + p);
        float4v wv = *(const float4v*)(ltr_w + p);
        *(float4v*)&wS[p] = wv;
#pragma unroll
        for (int q = 0; q < 4; ++q) {
            int pq = p + q, h = pq / 20, t = pq - h * 20;
            sS[h * 21 + t] = (float)hv[q];
            mS[h * 21 + t] = mv[q];
        }
    }
    __syncthreads();

    float val = 0.f;
    if (tid < 250) {
        int h = tid % 50, kq = tid / 50;   // kq in 0..4, k = kq*4+j
        float s[20], mm[20];
#pragma unroll
        for (int t = 0; t < 20; ++t) { s[t] = sS[h * 21 + t]; mm[t] = mS[h * 21 + t]; }
#pragma unroll
        for (int j = 0; j < 4; ++j) {
            int k = kq * 4 + j;
            float mu = -0.9f + 0.1f * (float)k;
            float ce = (k == 19) ? (-500000.0f * 1.44269504f) : (-50.0f * 1.44269504f);
            float psum = 0.f;
#pragma unroll
            for (int t = 0; t < 20; ++t) {
                float d = s[t] - mu;
                psum += exp2f(d * d * ce) * mm[t];
            }
            val += __logf(fmaxf(psum, 1e-10f)) * wS[h * 20 + k];
        }
    }
#pragma unroll
    for (int off = 32; off; off >>= 1) val += __shfl_down(val, off);
    int wave = tid >> 6, lane = tid & 63;
    if (lane == 0) part[wave] = val;
    __syncthreads();
    if (tid == 0) {
        float tot = part[0] + part[1] + part[2] + part[3];
        rowsum[row] = tot * 0.01f * cpad[row];
    }
}

// ---------------- Kernel 4: sum rows per (b,c) + bias + log_softmax over C=5 ------------
__global__ __launch_bounds__(64) void finalize(const float* __restrict__ rowsum,
                                               const float* __restrict__ ltr_b,
                                               float* __restrict__ out)
{
    int b = blockIdx.x;
    int tid = threadIdx.x;
    __shared__ float sc[5];
    if (tid < 5) {
        float a = ltr_b[0];
        const float* rp = rowsum + (b * 5 + tid) * 20;
#pragma unroll
        for (int s = 0; s < 20; ++s) a += rp[s];
        sc[tid] = a;
    }
    __syncthreads();
    if (tid < 5) {
        float m = fmaxf(fmaxf(fmaxf(sc[0], sc[1]), fmaxf(sc[2], sc[3])), sc[4]);
        float sum = 0.f;
#pragma unroll
        for (int i = 0; i < 5; ++i) sum += __expf(sc[i] - m);
        out[b * 5 + tid] = sc[tid] - m - __logf(sum);
    }
}

extern "C" void kernel_launch(void* const* d_in, const int* in_sizes, int n_in,
                              void* d_out, int out_size, void* d_ws, size_t ws_size,
                              hipStream_t stream)
{
    const int*   cand = (const int*)d_in[0];
    const int*   clk  = (const int*)d_in[1];
    const float* cpad = (const float*)d_in[2];
    const float* hpad = (const float*)d_in[3];
    const float* emb  = (const float*)d_in[4];
    const float* lw   = (const float*)d_in[5];
    const float* lb   = (const float*)d_in[6];
    float* out = (float*)d_out;

    _Float16* wsH  = (_Float16*)d_ws;                                   // 22.528 MB
    _Float16* simW = (_Float16*)((char*)d_ws + (size_t)(NROW_CDD + NROW_HIS) * KP * 2);  // 6.4 MB
    float* rowsum  = (float*)((char*)simW + (size_t)B_ * 100 * 1000 * 2);                // 12.8 KB

    hipLaunchKernelGGL(gather_norm, dim3((NROW_CDD + NROW_HIS) / 4), dim3(256), 0, stream,
                       cand, clk, emb, wsH);
    hipLaunchKernelGGL(sim_gemm, dim3(8, B_), dim3(256), 0, stream, wsH, simW);
    hipLaunchKernelGGL(knrm_pool, dim3(NROW_CDD), dim3(256), 0, stream,
                       simW, cpad, hpad, lw, rowsum);
    hipLaunchKernelGGL(finalize, dim3(B_), dim3(64), 0, stream, rowsum, lb, out);
}